// Round 6
// baseline (7101.824 us; speedup 1.0000x reference)
//
#include <hip/hip_runtime.h>
#include <hip/hip_bf16.h>
#include <stdint.h>

#define B_SZ 2048
#define H_SZ 1024
#define S_SZ 128
#define G4   4096
#define BK   32
#define NKK  (H_SZ / BK)   // 32 K-tiles
#define BM   128           // batch rows per block
#define BN   256           // packed gate-cols per block
#define NJT  16            // G4/BN
#define NBLK 256

typedef short short8 __attribute__((ext_vector_type(8)));
typedef float floatx4 __attribute__((ext_vector_type(4)));

#define AS1 __attribute__((address_space(1)))
#define AS3 __attribute__((address_space(3)))

// Persistent device buffers (fully rewritten/reset on every kernel_launch).
// W and h global layouts are XOR-swizzled within each 64B chunk-group:
// stored elem = k ^ ((row&3)<<3). Staging reads LINEAR source addresses, so
// LDS receives the swizzled data; ds_read applies the same XOR to undo it.
// (Round-5 bug: applying the XOR to the staging source too cancels the
// swizzle -> linear LDS + XOR'd read = wrong K-slices.)
__device__ ushort g_Wp[G4 * H_SZ];       // packed W_hh bf16, row j=(h/16)*64+gate*16+(h%16)
__device__ ushort g_h[2][B_SZ * H_SZ];   // hidden bf16, swizzled cols
__device__ float  g_wih[G4];             // packed W_ih
__device__ float  g_bias[G4];            // packed b_ih + b_hh
__device__ float  g_pp[2][NJT][B_SZ];    // per-jt pred partials, ping-pong by t&1
__device__ unsigned g_leaf[8 * 32];      // barrier leaves (1 per XCD group, 128B apart)
__device__ unsigned g_root;
__device__ unsigned g_gen;

__device__ __forceinline__ float bf2f(ushort u) {
  return __uint_as_float(((unsigned)u) << 16);
}
__device__ __forceinline__ ushort f2bf(float f) {
  unsigned u = __float_as_uint(f);
  return (ushort)((u + 0x7FFFu + ((u >> 16) & 1u)) >> 16);
}
__device__ __forceinline__ float fsig(float x) { return 1.f / (1.f + __expf(-x)); }
__device__ __forceinline__ float ftanh(float x) { return 1.f - 2.f / (__expf(2.f * x) + 1.f); }

__device__ __forceinline__ void gload16(const void* g, void* l) {
  __builtin_amdgcn_global_load_lds((const AS1 void*)g, (AS3 void*)l, 16, 0, 0);
}

// Two-level grid barrier (leaf per XCD-group of 32 blocks, then root of 8).
// Agent-scope atomics; __threadfence() = agent wb/inv of L1+L2 for visibility.
__device__ __forceinline__ void grid_barrier(int grp) {
  __syncthreads();
  if (threadIdx.x == 0) {
    __threadfence();  // release: write back dirty L2 (h, g_pp)
    unsigned gen = __hip_atomic_load(&g_gen, __ATOMIC_RELAXED, __HIP_MEMORY_SCOPE_AGENT);
    unsigned a = __hip_atomic_fetch_add(&g_leaf[grp * 32], 1u, __ATOMIC_ACQ_REL,
                                        __HIP_MEMORY_SCOPE_AGENT);
    if (a == 31u) {
      __hip_atomic_store(&g_leaf[grp * 32], 0u, __ATOMIC_RELAXED, __HIP_MEMORY_SCOPE_AGENT);
      unsigned r = __hip_atomic_fetch_add(&g_root, 1u, __ATOMIC_ACQ_REL,
                                          __HIP_MEMORY_SCOPE_AGENT);
      if (r == 7u) {
        __hip_atomic_store(&g_root, 0u, __ATOMIC_RELAXED, __HIP_MEMORY_SCOPE_AGENT);
        __hip_atomic_store(&g_gen, gen + 1u, __ATOMIC_RELEASE, __HIP_MEMORY_SCOPE_AGENT);
      } else {
        while (__hip_atomic_load(&g_gen, __ATOMIC_RELAXED, __HIP_MEMORY_SCOPE_AGENT) == gen)
          __builtin_amdgcn_s_sleep(2);
      }
    } else {
      while (__hip_atomic_load(&g_gen, __ATOMIC_RELAXED, __HIP_MEMORY_SCOPE_AGENT) == gen)
        __builtin_amdgcn_s_sleep(2);
    }
    __threadfence();  // acquire: invalidate stale L1/L2 lines
  }
  __syncthreads();
}

// ---------------- prep kernels ----------------

__global__ __launch_bounds__(256) void prep_wpack(const float* __restrict__ Whh) {
  const int gid = blockIdx.x * 256 + threadIdx.x;  // 524288
  const int j   = gid >> 7;                        // packed row 0..4095
  const int k8  = (gid & 127) << 3;                // elem offset
  const int gate = (j >> 4) & 3;
  const int h    = ((j >> 6) << 4) | (j & 15);
  const float* src = Whh + (size_t)(gate * H_SZ + h) * H_SZ + k8;
  floatx4 a = *(const floatx4*)src;
  floatx4 b = *(const floatx4*)(src + 4);
  short8 o;
#pragma unroll
  for (int i = 0; i < 4; ++i) o[i] = (short)f2bf(a[i]);
#pragma unroll
  for (int i = 0; i < 4; ++i) o[4 + i] = (short)f2bf(b[i]);
  *(short8*)&g_Wp[(size_t)j * H_SZ + (k8 ^ ((j & 3) << 3))] = o;
}

__global__ __launch_bounds__(256) void prep_misc(const float* __restrict__ Wih,
                                                 const float* __restrict__ bih,
                                                 const float* __restrict__ bhh) {
  if (blockIdx.x == 0) {  // reset barrier state every call (determinism)
    if (threadIdx.x == 0) { g_root = 0u; g_gen = 0u; }
    if (threadIdx.x < 8) g_leaf[threadIdx.x * 32] = 0u;
  }
  const int j = blockIdx.x * 256 + threadIdx.x;  // 4096
  const int gate = (j >> 4) & 3;
  const int h    = ((j >> 6) << 4) | (j & 15);
  const int jp   = gate * H_SZ + h;
  g_wih[j]  = Wih[jp];
  g_bias[j] = bih[jp] + bhh[jp];
}

__global__ __launch_bounds__(256) void prep_h(const float* __restrict__ hidden) {
  const int gid = blockIdx.x * 256 + threadIdx.x;  // 262144
  const int row = gid >> 7;
  const int k8  = (gid & 127) << 3;
  const size_t src = (size_t)row * H_SZ + k8;
  short8 o;
#pragma unroll
  for (int i = 0; i < 8; ++i) o[i] = (short)f2bf(hidden[src + i]);
  *(short8*)&g_h[0][(size_t)row * H_SZ + (k8 ^ ((row & 3) << 3))] = o;
}

// ---------------- persistent all-steps kernel ----------------
// 256 blocks (exactly 1/CU -> co-residency by construction), 512 threads.
// Block = 128 batch rows x 256 packed gate-cols. XCD x (bid&7) owns
// jt in {(x&3)*4..+3} and bt in {(x>>2)*8..+7} -> ~2MB W + ~2MB h per L2.
__global__ __launch_bounds__(512, 2)
void lstm_persistent(const float* __restrict__ cell,
                     const float* __restrict__ Wfc,
                     const float* __restrict__ bfc,
                     float* __restrict__ out) {
  __shared__ ushort Al[2][BM * BK];   // 2 x 8KB
  __shared__ ushort Bl[2][BN * BK];   // 2 x 16KB
  __shared__ float  xbuf[BM];
  __shared__ float  predp[4 * BM];

  const int tid  = threadIdx.x;
  const int lane = tid & 63;
  const int wid  = tid >> 6;                  // 0..7
  const int bid  = blockIdx.x;
  const int grp  = bid & 7;                   // XCD (hw round-robin)
  const int idx  = bid >> 3;                  // 0..31
  const int jt   = (grp & 3) * 4 + (idx & 3); // 0..15
  const int bt   = (grp >> 2) * 8 + (idx >> 2);
  const int brow = bt * BM;
  const int jcol = jt * BN;
  const int wr = wid >> 2, wc = wid & 3;      // wave tile: 2 x 4
  const int lr = lane & 15, lk = lane >> 4;

  // staging geometry: thread stages one 16B chunk of A, two of B per phase.
  // Source addresses are LINEAR; the global layout carries the swizzle.
  const int srow   = wid * 16 + (lane >> 2);  // 0..127
  const int schunk = (lane & 3) << 3;
  const size_t abase  = (size_t)(brow + srow) * H_SZ + schunk;
  const size_t bbase0 = (size_t)(jcol + srow) * H_SZ + schunk;
  const size_t bbase1 = bbase0 + (size_t)128 * H_SZ;

  int aoff[4], boff[4];
#pragma unroll
  for (int m = 0; m < 4; ++m) aoff[m] = (wr * 64 + m * 16 + lr) * BK;
#pragma unroll
  for (int n = 0; n < 4; ++n) boff[n] = (wc * 64 + n * 16 + lr) * BK;
  const int cc = (lk * 8) ^ ((lr & 3) << 3);

  // hoisted epilogue constants
  const int hcol = jt * 64 + wc * 16 + lr;    // global h index 0..1023
  float wih[4], bb[4];
#pragma unroll
  for (int n = 0; n < 4; ++n) {
    const int col = jcol + wc * 64 + n * 16 + lr;
    wih[n] = g_wih[col];
    bb[n]  = g_bias[col];
  }

  // cell state in registers for the whole sequence
  float creg[4][4];
#pragma unroll
  for (int m = 0; m < 4; ++m)
#pragma unroll
    for (int r = 0; r < 4; ++r) {
      const int row_l = wr * 64 + m * 16 + lk * 4 + r;
      creg[m][r] = cell[(size_t)(brow + row_l) * H_SZ + hcol];
    }

#define STAGE(BUF, KO)                                                      \
  {                                                                         \
    const int ko_ = (KO) * BK;                                              \
    gload16(hin + abase + ko_, &Al[BUF][wid * 512]);                        \
    gload16(g_Wp + bbase0 + ko_, &Bl[BUF][wid * 512]);                      \
    gload16(g_Wp + bbase1 + ko_, &Bl[BUF][4096 + wid * 512]);               \
  }

#define COMPUTE(BUF)                                                        \
  {                                                                         \
    short8 a[4], b[4];                                                      \
    _Pragma("unroll") for (int m = 0; m < 4; ++m)                           \
        a[m] = *(const short8*)&Al[BUF][aoff[m] + cc];                      \
    _Pragma("unroll") for (int n = 0; n < 4; ++n)                           \
        b[n] = *(const short8*)&Bl[BUF][boff[n] + cc];                      \
    _Pragma("unroll") for (int m = 0; m < 4; ++m)                           \
        _Pragma("unroll") for (int n = 0; n < 4; ++n)                       \
            acc[m][n] = __builtin_amdgcn_mfma_f32_16x16x32_bf16(            \
                a[m], b[n], acc[m][n], 0, 0, 0);                            \
  }

  for (int t = 0; t < S_SZ; ++t) {
    const int p = t & 1;
    const ushort* __restrict__ hin = g_h[p];
    ushort* __restrict__ hout      = g_h[p ^ 1];

    floatx4 acc[4][4];
#pragma unroll
    for (int m = 0; m < 4; ++m)
#pragma unroll
      for (int n = 0; n < 4; ++n) acc[m][n] = {0.f, 0.f, 0.f, 0.f};

    STAGE(0, 0);
    __syncthreads();

    for (int kk = 0; kk < NKK; kk += 2) {
      STAGE(1, kk + 1);           // issue next-tile loads first
      COMPUTE(0);                 // compute current under load latency
      __syncthreads();            // drains vmcnt -> buf1 ready
      if (kk + 2 < NKK) STAGE(0, kk + 2);
      COMPUTE(1);
      __syncthreads();
    }

    // ---------------- epilogue ----------------
    if (t > 0 && tid < BM) {
      float s = 0.f;
#pragma unroll
      for (int j = 0; j < NJT; ++j) s += g_pp[(t - 1) & 1][j][brow + tid];
      s += bfc[t - 1];
      xbuf[tid] = s;
      if (jt == 0) out[(size_t)(brow + tid) * S_SZ + (t - 1)] = s;
    }
    __syncthreads();

    const float wfc_l = Wfc[(size_t)t * H_SZ + hcol];  // own-step head weight

#pragma unroll
    for (int m = 0; m < 4; ++m) {
#pragma unroll
      for (int r = 0; r < 4; ++r) {
        const int row_l = wr * 64 + m * 16 + lk * 4 + r;
        const float xv = (t > 0) ? xbuf[row_l] : 0.f;
        float gi = acc[m][0][r] + xv * wih[0] + bb[0];
        float gf = acc[m][1][r] + xv * wih[1] + bb[1];
        float gg = acc[m][2][r] + xv * wih[2] + bb[2];
        float go = acc[m][3][r] + xv * wih[3] + bb[3];
        float cn = fsig(gf) * creg[m][r] + fsig(gi) * ftanh(gg);
        creg[m][r] = cn;
        float hv = fsig(go) * ftanh(cn);
        // (row_l&3)==r, so the column swizzle is r<<3
        hout[(size_t)(brow + row_l) * H_SZ + (hcol ^ (r << 3))] = f2bf(hv);
        // own-step head partial: pred_t[row] += h_t[row,hcol] * Wfc[t,hcol]
        float pp = hv * wfc_l;
        pp += __shfl_xor(pp, 1);
        pp += __shfl_xor(pp, 2);
        pp += __shfl_xor(pp, 4);
        pp += __shfl_xor(pp, 8);
        if (lr == 0) predp[wc * BM + row_l] = pp;
      }
    }
    __syncthreads();
    if (tid < BM)
      g_pp[p][jt][brow + tid] = predp[tid] + predp[BM + tid] +
                                predp[2 * BM + tid] + predp[3 * BM + tid];

    grid_barrier(grp);
  }

  // final head output for t = S-1 (127 is odd -> partials in g_pp[1])
  if (jt == 0 && tid < BM) {
    float s = 0.f;
#pragma unroll
    for (int j = 0; j < NJT; ++j) s += g_pp[1][j][brow + tid];
    out[(size_t)(brow + tid) * S_SZ + (S_SZ - 1)] = s + bfc[S_SZ - 1];
  }
#undef STAGE
#undef COMPUTE
}

extern "C" void kernel_launch(void* const* d_in, const int* in_sizes, int n_in,
                              void* d_out, int out_size, void* d_ws, size_t ws_size,
                              hipStream_t stream) {
  const float* hidden = (const float*)d_in[0];
  const float* cell   = (const float*)d_in[1];
  const float* W_ih   = (const float*)d_in[2];
  const float* W_hh   = (const float*)d_in[3];
  const float* b_ih   = (const float*)d_in[4];
  const float* b_hh   = (const float*)d_in[5];
  const float* W_fc   = (const float*)d_in[6];
  const float* b_fc   = (const float*)d_in[7];
  float* out = (float*)d_out;

  prep_wpack<<<2048, 256, 0, stream>>>(W_hh);
  prep_misc<<<16, 256, 0, stream>>>(W_ih, b_ih, b_hh);
  prep_h<<<1024, 256, 0, stream>>>(hidden);

  lstm_persistent<<<NBLK, 512, 0, stream>>>(cell, W_fc, b_fc, out);
}